// Round 9
// baseline (444.500 us; speedup 1.0000x reference)
//
#include <hip/hip_runtime.h>
#include <math.h>

#define BB 16
#define TT 144
#define TP1 145
#define HW4 4096   // f4 groups per image
#define HW8 2048   // u16x8 groups per image (also f8 groups)
#define HWF2 8192  // float2 groups per image
#define LL 6
#define BIGE 1e30
#define EPSQ 7.62951e-6  // 0.5/65535 quantization bound on w in [0,1]
#define RB 37            // build: 36 blocks x 4 rows + 1 special per batch
#define NBLK (BB * RB)   // 592
#define BCHUNK 74        // 592/8
#define RCHUNK 290       // 2320/8 (fallback kernels)

typedef float          f4    __attribute__((ext_vector_type(4)));
typedef float          f8    __attribute__((ext_vector_type(8)));
typedef unsigned short u16x4 __attribute__((ext_vector_type(4)));
typedef unsigned short u16x8 __attribute__((ext_vector_type(8)));
typedef unsigned long long ull;

// ---- workspace layout (bytes) ----
// State streams: M (mask product), R = x - A.
static const size_t OFF_M    = 0;                   // B*HW f32 (1 MB)
static const size_t OFF_R    = 1u << 20;            // B*HW f32
static const size_t OFF_E32  = 2u << 20;            // B*145 f64 (build exact scores)
static const size_t OFF_E16  = (2u << 20) + 32768;  // B*145 f64 (screen accumulators)
static const size_t OFF_D    = (2u << 20) + 65536;  // B f64
static const size_t OFF_USED = (2u << 20) + 81920;  // B*145 i32
static const size_t OFF_SEL  = (2u << 20) + 98304;  // B i32
static const size_t OFF_WQ   = 3u << 20;            // B*T*HW u16 = 75,497,472
static const size_t WS_FULL  = OFF_WQ + 75497472ull;

__device__ __forceinline__ float hsum(f4 v) { return ((v.x + v.y) + v.z) + v.w; }
__device__ __forceinline__ float hsum8(f8 v) {
    return (((v.s0 + v.s1) + (v.s2 + v.s3)) + ((v.s4 + v.s5) + (v.s6 + v.s7)));
}
__device__ __forceinline__ f8 fabs8(f8 v) {
    f8 o;
    o.s0 = __builtin_fabsf(v.s0); o.s1 = __builtin_fabsf(v.s1);
    o.s2 = __builtin_fabsf(v.s2); o.s3 = __builtin_fabsf(v.s3);
    o.s4 = __builtin_fabsf(v.s4); o.s5 = __builtin_fabsf(v.s5);
    o.s6 = __builtin_fabsf(v.s6); o.s7 = __builtin_fabsf(v.s7);
    return o;
}

__device__ __forceinline__ double wave_reduce_d(double s) {
    for (int off = 32; off; off >>= 1) s += __shfl_down(s, off);
    return s;  // valid in lane 0
}

__device__ __forceinline__ double blk_reduce(double s) {
    for (int off = 32; off; off >>= 1) s += __shfl_down(s, off);
    __shared__ double smr[4];
    if ((threadIdx.x & 63) == 0) smr[threadIdx.x >> 6] = s;
    __syncthreads();
    double r = smr[0] + smr[1] + smr[2] + smr[3];
    __syncthreads();
    return r;
}

__device__ __forceinline__ void blk_reduce2(double& a, double& b) {
    for (int off = 32; off; off >>= 1) { a += __shfl_down(a, off); b += __shfl_down(b, off); }
    __shared__ double sa[4], sb[4];
    if ((threadIdx.x & 63) == 0) { sa[threadIdx.x >> 6] = a; sb[threadIdx.x >> 6] = b; }
    __syncthreads();
    a = sa[0] + sa[1] + sa[2] + sa[3];
    b = sb[0] + sb[1] + sb[2] + sb[3];
    __syncthreads();
}

__device__ __forceinline__ void blk_reduce4(double s[4]) {
    for (int off = 32; off; off >>= 1) {
        s[0] += __shfl_down(s[0], off); s[1] += __shfl_down(s[1], off);
        s[2] += __shfl_down(s[2], off); s[3] += __shfl_down(s[3], off);
    }
    __shared__ double sm4[4][4];
    const int wv = threadIdx.x >> 6;
    if ((threadIdx.x & 63) == 0) {
        sm4[wv][0] = s[0]; sm4[wv][1] = s[1]; sm4[wv][2] = s[2]; sm4[wv][3] = s[3];
    }
    __syncthreads();
    for (int k = 0; k < 4; ++k) s[k] = sm4[0][k] + sm4[1][k] + sm4[2][k] + sm4[3][k];
}

// Build wq = u16(round(65535*w)), w = t*m + bg*(1-m); exact step-0 scores; zero used[].
__global__ void k_build(const f4* __restrict__ temps, const f4* __restrict__ masks,
                        const f4* __restrict__ bg, const f4* __restrict__ x,
                        u16x4* __restrict__ wq, double* __restrict__ err32,
                        int* __restrict__ used) {
    const int lin = blockIdx.x;
    const int wg = (lin & 7) * BCHUNK + (lin >> 3);
    const int b = wg / RB, rg = wg - b * RB;
    const int tid = threadIdx.x;
    const f4* xb = x + (size_t)b * HW4;
    if (rg == RB - 1) {   // t = 0: w = 5 exactly
        if (tid < TP1) used[b * TP1 + tid] = 0;
        double s = 0.0;
        for (int j = tid; j < HW4; j += 256) {
            f4 d = 5.f - xb[j];
            s += (double)hsum(d * d);
        }
        double tot = blk_reduce(s);
        if (tid == 0) err32[b * TP1 + 0] = tot;
        return;
    }
    const int tbase = 1 + rg * 4;
    const size_t r0 = ((size_t)(b * TT + tbase - 1)) * HW4;
    const size_t r1 = r0 + HW4, r2 = r1 + HW4, r3 = r2 + HW4;
    double s[4] = {0.0, 0.0, 0.0, 0.0};
    #pragma unroll 2
    for (int j = tid; j < HW4; j += 256) {
        f4 bv = bg[j], xv = xb[j];
        f4 tv0 = __builtin_nontemporal_load(&temps[r0 + j]);
        f4 mv0 = __builtin_nontemporal_load(&masks[r0 + j]);
        f4 w0 = tv0 * mv0 + bv * (1.f - mv0);
        wq[r0 + j] = __builtin_convertvector(w0 * 65535.f + 0.5f, u16x4);
        f4 d0 = w0 - xv; s[0] += (double)hsum(d0 * d0);
        f4 tv1 = __builtin_nontemporal_load(&temps[r1 + j]);
        f4 mv1 = __builtin_nontemporal_load(&masks[r1 + j]);
        f4 w1 = tv1 * mv1 + bv * (1.f - mv1);
        wq[r1 + j] = __builtin_convertvector(w1 * 65535.f + 0.5f, u16x4);
        f4 d1 = w1 - xv; s[1] += (double)hsum(d1 * d1);
        f4 tv2 = __builtin_nontemporal_load(&temps[r2 + j]);
        f4 mv2 = __builtin_nontemporal_load(&masks[r2 + j]);
        f4 w2 = tv2 * mv2 + bv * (1.f - mv2);
        wq[r2 + j] = __builtin_convertvector(w2 * 65535.f + 0.5f, u16x4);
        f4 d2 = w2 - xv; s[2] += (double)hsum(d2 * d2);
        f4 tv3 = __builtin_nontemporal_load(&temps[r3 + j]);
        f4 mv3 = __builtin_nontemporal_load(&masks[r3 + j]);
        f4 w3 = tv3 * mv3 + bv * (1.f - mv3);
        wq[r3 + j] = __builtin_convertvector(w3 * 65535.f + 0.5f, u16x4);
        f4 d3 = w3 - xv; s[3] += (double)hsum(d3 * d3);
    }
    blk_reduce4(s);
    if (tid == 0)
        for (int k = 0; k < 4; ++k) err32[b * TP1 + tbase + k] = s[k];
}

// Resolve selection for step l: argmin (+ sound margin shortlist on SCREEN scores,
// rare exact re-eval), write sel[b] + ids + used; zero err16/Dd for the next step.
// One block per batch (16 blocks).
template <bool EXACT>
__global__ void k_resolve(const f4* __restrict__ temps, const f4* __restrict__ masks,
                          const f4* __restrict__ bg,
                          const f4* __restrict__ Mst, const f4* __restrict__ Rst,
                          const double* __restrict__ scr, double* __restrict__ zbuf,
                          double* __restrict__ Dd, int* __restrict__ used,
                          int* __restrict__ selp, float* __restrict__ out_ids, int l) {
    const int b = blockIdx.x;
    const int tid = threadIdx.x;
    const double* sb = scr + (size_t)b * TP1;
    __shared__ int s_sel, s_cnt;
    __shared__ ull s_mask[3];
    if (tid < 64) {
        double e0 = sb[tid];
        double e1 = (tid + 64 < TP1) ? sb[tid + 64] : 1e301;
        double e2 = (tid + 128 < TP1) ? sb[tid + 128] : 1e301;
        if (!EXACT) {
            if (tid != 0 && used[b * TP1 + tid]) e0 = BIGE;
            if (tid + 64 < TP1 && used[b * TP1 + tid + 64]) e1 = BIGE;
            if (tid + 128 < TP1 && used[b * TP1 + tid + 128]) e2 = BIGE;
        }
        double best = e0; int bi = tid;
        if (e1 < best) { best = e1; bi = tid + 64; }
        if (e2 < best) { best = e2; bi = tid + 128; }
        for (int off = 32; off; off >>= 1) {
            double oe = __shfl_down(best, off);
            int    oi = __shfl_down(bi, off);
            if (oe < best || (oe == best && oi < bi)) { best = oe; bi = oi; }
        }
        best = __shfl(best, 0); bi = __shfl(bi, 0);
        if (EXACT) {
            if (tid == 0) { s_sel = bi; s_cnt = 1; }
        } else {
            const double thr = best + (6.0 * EPSQ * Dd[b] + 0.15);
            ull m0 = __ballot(e0 <= thr);
            ull m1 = __ballot(e1 <= thr);
            ull m2 = __ballot(e2 <= thr);
            if (tid == 0) {
                s_mask[0] = m0; s_mask[1] = m1; s_mask[2] = m2;
                s_cnt = __popcll(m0) + __popcll(m1) + __popcll(m2);
                s_sel = bi;   // screen argmin (final if singleton)
            }
        }
    }
    __syncthreads();
    if (!EXACT && s_cnt > 1) {
        // rare: exact f32 evals of shortlist members, ascending t, strict < tie-break
        __shared__ double s_beste; __shared__ int s_besti;
        if (tid == 0) { s_beste = 1e301; s_besti = -1; }
        __syncthreads();
        const f4* Mb = Mst + (size_t)b * HW4;
        const f4* Rb = Rst + (size_t)b * HW4;
        for (int t = 0; t < TP1; ++t) {
            if (!((s_mask[t >> 6] >> (t & 63)) & 1ull)) continue;
            double s;
            if (t == 0) {
                s = sb[0];   // exact-form already
            } else {
                const size_t row = ((size_t)(b * TT + t - 1)) * HW4;
                double acc = 0.0;
                for (int j = tid; j < HW4; j += 256) {
                    f4 tv = temps[row + j], mv = masks[row + j], bv = bg[j];
                    f4 w = tv * mv + bv * (1.f - mv);
                    f4 d = w * Mb[j] - Rb[j];
                    acc += (double)hsum(d * d);
                }
                s = blk_reduce(acc);
            }
            if (tid == 0 && s < s_beste) { s_beste = s; s_besti = t; }
            __syncthreads();
        }
        if (tid == 0) s_sel = s_besti;
        __syncthreads();
    }
    const int sel = s_sel;
    if (tid == 0) {
        selp[b] = sel;
        out_ids[b * LL + l] = (float)sel;
        if (sel != 0) used[b * TP1 + sel] = 1;
        Dd[b] = 0.0;
    }
    // zero the screen accumulators for the next fused pass (after all reads)
    for (int t = tid; t < TP1; t += 256) zbuf[(size_t)b * TP1 + t] = 0.0;
}

// Fused: apply selection l on this block's exclusive 512-px slice (state in regs),
// then (unless LAST) accumulate next step's screen scores for ALL 144 candidates
// over the slice via one f64 atomicAdd per wave per row. LAST emits recons instead.
template <bool FIRST, bool LAST>
__global__ __launch_bounds__(256) void k_fused(
    const float2* __restrict__ temps2, const float2* __restrict__ masks2,
    const float2* __restrict__ x2, const float2* __restrict__ bg2,
    const u16x8* __restrict__ wq, const int* __restrict__ selp,
    float2* __restrict__ Mst2, float2* __restrict__ Rst2,
    double* __restrict__ err16, double* __restrict__ Dd,
    float2* __restrict__ out_obj2, float2* __restrict__ out_msk2,
    float2* __restrict__ out_rec2, int l) {
    const int lin = blockIdx.x;
    const int wg = (lin & 7) * 64 + (lin >> 3);   // 512 = 8*64 bijective XCD swizzle
    const int b = wg >> 5;                        // 32 slices per batch
    const int s = wg & 31;
    const int tid = threadIdx.x;
    const int sel = selp[b];
    const int P = s * 512;                        // pixel base of slice
    const size_t g2 = (size_t)b * HWF2 + (P >> 1) + tid;   // this thread's float2

    float2 xv = x2[g2];
    float2 st, sm;
    if (sel == 0) { st = make_float2(5.f, 5.f); sm = make_float2(1.f, 1.f); }
    else {
        size_t base2 = ((size_t)(b * TT + sel - 1)) * HWF2 + (P >> 1) + tid;
        st = temps2[base2]; sm = masks2[base2];
    }
    float2 a, mp;
    if (FIRST) { a = make_float2(0.f, 0.f); mp = make_float2(1.f, 1.f); }
    else {
        mp = Mst2[g2];
        float2 rr0 = Rst2[g2];
        a = make_float2(xv.x - rr0.x, xv.y - rr0.y);
    }
    a.x += mp.x * st.x * sm.x;  mp.x *= (1.f - sm.x);
    a.y += mp.y * st.y * sm.y;  mp.y *= (1.f - sm.y);
    const size_t ob2 = ((size_t)(b * LL + l)) * HWF2 + (P >> 1) + tid;
    out_obj2[ob2] = st;
    out_msk2[ob2] = sm;
    if (LAST) {
        float2 bv = bg2[(P >> 1) + tid];
        out_rec2[g2] = make_float2(a.x + mp.x * bv.x, a.y + mp.y * bv.y);
        return;
    }
    float2 rr = make_float2(xv.x - a.x, xv.y - a.y);
    Mst2[g2] = mp;
    Rst2[g2] = rr;
    // t=0 exact-form score + margin accumulator D over this slice
    float d0x = 5.f * mp.x - rr.x, d0y = 5.f * mp.y - rr.y;
    double t0 = (double)(d0x * d0x + d0y * d0y);
    double dD = (double)(mp.x * (mp.x + __builtin_fabsf(rr.x)) +
                         mp.y * (mp.y + __builtin_fabsf(rr.y)));
    blk_reduce2(t0, dD);
    if (tid == 0) {
        atomicAdd(&err16[(size_t)b * TP1 + 0], t0);
        atomicAdd(&Dd[b], dD);
    }
    // exchange ms, r through LDS so phase-2 lanes own 8 contiguous px each
    __shared__ float lms[512], lr[512];
    lms[tid * 2]     = mp.x * (1.f / 65535.f);
    lms[tid * 2 + 1] = mp.y * (1.f / 65535.f);
    lr[tid * 2]      = rr.x;
    lr[tid * 2 + 1]  = rr.y;
    __syncthreads();
    const int lane = tid & 63, w = tid >> 6;
    float ms8[8], r8[8];
    #pragma unroll
    for (int k = 0; k < 8; ++k) { ms8[k] = lms[lane * 8 + k]; r8[k] = lr[lane * 8 + k]; }
    // screen: wave w handles rows w, w+4, ... (36 rows), 2-way unrolled
    const size_t rowbase = (size_t)b * TT * HW8 + (size_t)(P >> 3) + lane;
    double* eb = err16 + (size_t)b * TP1 + 1;
    for (int t = w; t < TT; t += 8) {
        u16x8 qa = wq[rowbase + (size_t)t * HW8];
        u16x8 qb = wq[rowbase + (size_t)(t + 4) * HW8];
        f8 fa = __builtin_convertvector(qa, f8);
        f8 fb = __builtin_convertvector(qb, f8);
        float ga = 0.f, gb = 0.f;
        #pragma unroll
        for (int k = 0; k < 8; ++k) {
            float da = fa[k] * ms8[k] - r8[k];
            float db = fb[k] * ms8[k] - r8[k];
            ga += da * da;
            gb += db * db;
        }
        double sa = wave_reduce_d((double)ga);
        double sb = wave_reduce_d((double)gb);
        if (lane == 0) {
            atomicAdd(&eb[t], sa);
            atomicAdd(&eb[t + 4], sb);
        }
    }
}

// ---------- fallback path (small ws): exact d-form per (b,t) ----------
__global__ void k_init0(const f4* __restrict__ x, f4* __restrict__ Mst, f4* __restrict__ Rst,
                        int* __restrict__ used) {
    int gid = blockIdx.x * blockDim.x + threadIdx.x;
    if (gid < BB * TP1) used[gid] = 0;
    if (gid >= BB * HW4) return;
    Mst[gid] = (f4){1.f, 1.f, 1.f, 1.f};
    Rst[gid] = x[gid];
}

__global__ void k_errfb(const f4* __restrict__ temps, const f4* __restrict__ masks,
                        const f4* __restrict__ bg,
                        const f4* __restrict__ Mst, const f4* __restrict__ Rst,
                        const int* __restrict__ used, double* __restrict__ err32) {
    const int lin = blockIdx.x;
    const int wg = (lin & 7) * RCHUNK + (lin >> 3);
    const int b = wg / TP1, t = wg - b * TP1;
    const int tid = threadIdx.x;
    if (t != 0 && used[b * TP1 + t]) {
        if (tid == 0) err32[b * TP1 + t] = BIGE;
        return;
    }
    const f4* Mb = Mst + (size_t)b * HW4;
    const f4* Rb = Rst + (size_t)b * HW4;
    double s = 0.0;
    if (t == 0) {
        for (int j = tid; j < HW4; j += 256) {
            f4 d = Mb[j] * 5.f - Rb[j];
            s += (double)hsum(d * d);
        }
    } else {
        const size_t row = ((size_t)(b * TT + t - 1)) * HW4;
        for (int j = tid; j < HW4; j += 256) {
            f4 tv = temps[row + j], mv = masks[row + j], bv = bg[j];
            f4 w = tv * mv + bv * (1.f - mv);
            f4 d = w * Mb[j] - Rb[j];
            s += (double)hsum(d * d);
        }
    }
    double tot = blk_reduce(s);
    if (tid == 0) err32[b * TP1 + t] = tot;
}

template <bool FIRST, bool LAST>
__global__ void k_updfb(const f4* __restrict__ temps, const f4* __restrict__ masks,
                        const f4* __restrict__ x, const f4* __restrict__ bg,
                        const double* __restrict__ err,
                        int* __restrict__ used, f4* __restrict__ Mst, f4* __restrict__ Rst,
                        f4* __restrict__ out_obj, f4* __restrict__ out_msk,
                        f4* __restrict__ out_rec, float* __restrict__ out_ids, int l) {
    const int tid = threadIdx.x;
    const int gid = blockIdx.x * 256 + tid;
    const int b = gid >> 12;
    const int p = gid & (HW4 - 1);
    __shared__ int ssel;
    if (tid < 64) {
        double best = 1e301; int bi = TP1;
        for (int t = tid; t < TP1; t += 64) {
            double e = err[b * TP1 + t];
            if (e < best) { best = e; bi = t; }
        }
        for (int off = 32; off; off >>= 1) {
            double oe = __shfl_down(best, off);
            int    oi = __shfl_down(bi, off);
            if (oe < best || (oe == best && oi < bi)) { best = oe; bi = oi; }
        }
        if (tid == 0) ssel = bi;
    }
    __syncthreads();
    const int id = ssel;
    f4 st, sm_;
    if (id == 0) { st = (f4){5.f,5.f,5.f,5.f}; sm_ = (f4){1.f,1.f,1.f,1.f}; }
    else {
        size_t base = ((size_t)(b * TT + id - 1)) * HW4 + p;
        st = temps[base]; sm_ = masks[base];
    }
    f4 xv = x[gid];
    f4 a, mp;
    if (FIRST) { a = (f4){0.f,0.f,0.f,0.f}; mp = (f4){1.f,1.f,1.f,1.f}; }
    else       { mp = Mst[gid]; a = xv - Rst[gid]; }
    a = a + mp * st * sm_;
    mp = mp * (1.f - sm_);
    const size_t ob = ((size_t)(b * LL + l)) * HW4 + p;
    out_obj[ob] = st;
    out_msk[ob] = sm_;
    if (LAST) {
        out_rec[gid] = a + mp * bg[p];
    } else {
        Mst[gid] = mp;
        Rst[gid] = xv - a;
    }
    if ((blockIdx.x & 15) == 0 && tid == 0) {
        if (id != 0) used[b * TP1 + id] = 1;
        out_ids[b * LL + l] = (float)id;
    }
}

extern "C" void kernel_launch(void* const* d_in, const int* in_sizes, int n_in,
                              void* d_out, int out_size, void* d_ws, size_t ws_size,
                              hipStream_t stream) {
    const f4* x     = (const f4*)d_in[0];
    const f4* temps = (const f4*)d_in[1];
    const f4* masks = (const f4*)d_in[2];
    const f4* bg    = (const f4*)d_in[3];

    float* out      = (float*)d_out;
    f4*    out_rec  = (f4*)out;                           // B*HW
    f4*    out_obj  = (f4*)(out + 262144);                // B*L*HW
    f4*    out_msk  = (f4*)(out + 262144 + 1572864);      // B*L*HW
    float* out_ids  = out + 262144 + 2 * 1572864;         // B*L

    char* ws = (char*)d_ws;
    f4*     Mst   = (f4*)(ws + OFF_M);
    f4*     Rst   = (f4*)(ws + OFF_R);
    double* err32 = (double*)(ws + OFF_E32);
    double* err16 = (double*)(ws + OFF_E16);
    double* Dd    = (double*)(ws + OFF_D);
    int*    used  = (int*)(ws + OFF_USED);
    int*    selp  = (int*)(ws + OFF_SEL);
    u16x4*  wq    = (u16x4*)(ws + OFF_WQ);

    const bool full = (ws_size >= WS_FULL);

    if (full) {
        k_build<<<NBLK, 256, 0, stream>>>(temps, masks, bg, x, wq, err32, used);
        // step 0: exact resolve on build scores (also zeros err16/Dd for step-1 screen)
        k_resolve<true><<<BB, 256, 0, stream>>>(temps, masks, bg, Mst, Rst,
                                                err32, err16, Dd, used, selp, out_ids, 0);
        k_fused<true, false><<<512, 256, 0, stream>>>(
            (const float2*)temps, (const float2*)masks, (const float2*)x, (const float2*)bg,
            (const u16x8*)wq, selp, (float2*)Mst, (float2*)Rst, err16, Dd,
            (float2*)out_obj, (float2*)out_msk, (float2*)out_rec, 0);
        for (int l = 1; l < LL; ++l) {
            k_resolve<false><<<BB, 256, 0, stream>>>(temps, masks, bg, Mst, Rst,
                                                     err16, err16, Dd, used, selp, out_ids, l);
            if (l < LL - 1)
                k_fused<false, false><<<512, 256, 0, stream>>>(
                    (const float2*)temps, (const float2*)masks, (const float2*)x, (const float2*)bg,
                    (const u16x8*)wq, selp, (float2*)Mst, (float2*)Rst, err16, Dd,
                    (float2*)out_obj, (float2*)out_msk, (float2*)out_rec, l);
            else
                k_fused<false, true><<<512, 256, 0, stream>>>(
                    (const float2*)temps, (const float2*)masks, (const float2*)x, (const float2*)bg,
                    (const u16x8*)wq, selp, (float2*)Mst, (float2*)Rst, err16, Dd,
                    (float2*)out_obj, (float2*)out_msk, (float2*)out_rec, l);
        }
    } else {
        k_init0<<<(BB * HW4 + 255) / 256, 256, 0, stream>>>(x, Mst, Rst, used);
        for (int l = 0; l < LL; ++l) {
            k_errfb<<<BB * TP1, 256, 0, stream>>>(temps, masks, bg, Mst, Rst, used, err32);
            if (l == 0)
                k_updfb<true, false><<<256, 256, 0, stream>>>(temps, masks, x, bg, err32, used,
                                                              Mst, Rst, out_obj, out_msk, out_rec, out_ids, l);
            else if (l == LL - 1)
                k_updfb<false, true><<<256, 256, 0, stream>>>(temps, masks, x, bg, err32, used,
                                                              Mst, Rst, out_obj, out_msk, out_rec, out_ids, l);
            else
                k_updfb<false, false><<<256, 256, 0, stream>>>(temps, masks, x, bg, err32, used,
                                                               Mst, Rst, out_obj, out_msk, out_rec, out_ids, l);
        }
    }
}

// Round 10
// 381.321 us; speedup vs baseline: 1.1657x; 1.1657x over previous
//
#include <hip/hip_runtime.h>
#include <math.h>

#define BB 16
#define TT 144
#define TP1 145
#define HW4 4096   // f4 groups per image
#define HW8 2048   // f8 / u16x8 groups per image
#define LL 6
#define BIGE 1e30
#define EPSQ 7.62951e-6  // 0.5/65535 quantization bound on w in [0,1]
#define RB 37            // build: 36 x 4-row blocks + 1 special, per batch
#define NBLK (BB * RB)   // 592
#define BCHUNK 74        // 592/8 (bijective XCD chunking)
#define RCHUNK 290       // 2320/8 (fallback kernels)

typedef float          f4    __attribute__((ext_vector_type(4)));
typedef float          f8    __attribute__((ext_vector_type(8)));
typedef unsigned short u16x4 __attribute__((ext_vector_type(4)));
typedef unsigned short u16x8 __attribute__((ext_vector_type(8)));
typedef unsigned long long ull;

// ---- workspace layout (bytes) ----
// Ping-pong state: M (mask product), R = x - A.  comb_l reads (l-1)&1, writes l&1.
static const size_t OFF_M0   = 0;                   // B*HW f32 (1 MB each)
static const size_t OFF_R0   = 1u << 20;
static const size_t OFF_M1   = 2u << 20;
static const size_t OFF_R1   = 3u << 20;
static const size_t OFF_E32  = 4u << 20;            // B*145 f64 (build exact scores)
static const size_t OFF_E16H = (4u << 20) + 32768;  // 2 x B*145 f64 (half partials)
static const size_t OFF_D    = (4u << 20) + 131072; // B f64
static const size_t OFF_USED = (4u << 20) + 147456; // B*145 i32
static const size_t OFF_SEL  = (4u << 20) + 163840; // B i32
static const size_t OFF_WQ   = 5u << 20;            // B*T*HW u16 = 75,497,472
static const size_t WS_FULL  = OFF_WQ + 75497472ull;

__device__ __forceinline__ float hsum(f4 v) { return ((v.x + v.y) + v.z) + v.w; }
__device__ __forceinline__ float hsum8(f8 v) {
    return (((v.s0 + v.s1) + (v.s2 + v.s3)) + ((v.s4 + v.s5) + (v.s6 + v.s7)));
}
__device__ __forceinline__ f8 fabs8(f8 v) {
    f8 o;
    o.s0 = __builtin_fabsf(v.s0); o.s1 = __builtin_fabsf(v.s1);
    o.s2 = __builtin_fabsf(v.s2); o.s3 = __builtin_fabsf(v.s3);
    o.s4 = __builtin_fabsf(v.s4); o.s5 = __builtin_fabsf(v.s5);
    o.s6 = __builtin_fabsf(v.s6); o.s7 = __builtin_fabsf(v.s7);
    return o;
}

__device__ __forceinline__ double blk_reduce(double s) {
    for (int off = 32; off; off >>= 1) s += __shfl_down(s, off);
    __shared__ double smr[4];
    if ((threadIdx.x & 63) == 0) smr[threadIdx.x >> 6] = s;
    __syncthreads();
    double r = smr[0] + smr[1] + smr[2] + smr[3];
    __syncthreads();
    return r;
}

__device__ __forceinline__ void blk_reduce2(double& a, double& b) {
    for (int off = 32; off; off >>= 1) { a += __shfl_down(a, off); b += __shfl_down(b, off); }
    __shared__ double sa[4], sb[4];
    if ((threadIdx.x & 63) == 0) { sa[threadIdx.x >> 6] = a; sb[threadIdx.x >> 6] = b; }
    __syncthreads();
    a = sa[0] + sa[1] + sa[2] + sa[3];
    b = sb[0] + sb[1] + sb[2] + sb[3];
    __syncthreads();
}

__device__ __forceinline__ void blk_reduce4(double s[4]) {
    for (int off = 32; off; off >>= 1) {
        s[0] += __shfl_down(s[0], off); s[1] += __shfl_down(s[1], off);
        s[2] += __shfl_down(s[2], off); s[3] += __shfl_down(s[3], off);
    }
    __shared__ double sm4[4][4];
    const int wv = threadIdx.x >> 6;
    if ((threadIdx.x & 63) == 0) {
        sm4[wv][0] = s[0]; sm4[wv][1] = s[1]; sm4[wv][2] = s[2]; sm4[wv][3] = s[3];
    }
    __syncthreads();
    for (int k = 0; k < 4; ++k) s[k] = sm4[0][k] + sm4[1][k] + sm4[2][k] + sm4[3][k];
}

__device__ __forceinline__ void blk_reduce8(double s[8]) {
    #pragma unroll
    for (int k = 0; k < 8; ++k)
        for (int off = 32; off; off >>= 1) s[k] += __shfl_down(s[k], off);
    __shared__ double sm8[4][8];
    const int wv = threadIdx.x >> 6;
    if ((threadIdx.x & 63) == 0) {
        #pragma unroll
        for (int k = 0; k < 8; ++k) sm8[wv][k] = s[k];
    }
    __syncthreads();
    #pragma unroll
    for (int k = 0; k < 8; ++k) s[k] = sm8[0][k] + sm8[1][k] + sm8[2][k] + sm8[3][k];
}

// Build wq = u16(round(65535*w)), w = t*m + bg*(1-m); exact step-0 scores
// err32 = sum((w-x)^2); zero used[]. temps/masks read-once -> non-temporal.
__global__ void k_build(const f4* __restrict__ temps, const f4* __restrict__ masks,
                        const f4* __restrict__ bg, const f4* __restrict__ x,
                        u16x4* __restrict__ wq, double* __restrict__ err32,
                        int* __restrict__ used) {
    const int lin = blockIdx.x;
    const int wg = (lin & 7) * BCHUNK + (lin >> 3);
    const int b = wg / RB, rg = wg - b * RB;
    const int tid = threadIdx.x;
    const f4* xb = x + (size_t)b * HW4;
    if (rg == RB - 1) {   // t = 0: w = 5 exactly
        if (tid < TP1) used[b * TP1 + tid] = 0;
        double s = 0.0;
        for (int j = tid; j < HW4; j += 256) {
            f4 d = 5.f - xb[j];
            s += (double)hsum(d * d);
        }
        double tot = blk_reduce(s);
        if (tid == 0) err32[b * TP1 + 0] = tot;
        return;
    }
    const int tbase = 1 + rg * 4;
    const size_t r0 = ((size_t)(b * TT + tbase - 1)) * HW4;
    const size_t r1 = r0 + HW4, r2 = r1 + HW4, r3 = r2 + HW4;
    double s[4] = {0.0, 0.0, 0.0, 0.0};
    #pragma unroll 2
    for (int j = tid; j < HW4; j += 256) {
        f4 bv = bg[j], xv = xb[j];
        f4 tv0 = __builtin_nontemporal_load(&temps[r0 + j]);
        f4 mv0 = __builtin_nontemporal_load(&masks[r0 + j]);
        f4 w0 = tv0 * mv0 + bv * (1.f - mv0);
        wq[r0 + j] = __builtin_convertvector(w0 * 65535.f + 0.5f, u16x4);
        f4 d0 = w0 - xv; s[0] += (double)hsum(d0 * d0);
        f4 tv1 = __builtin_nontemporal_load(&temps[r1 + j]);
        f4 mv1 = __builtin_nontemporal_load(&masks[r1 + j]);
        f4 w1 = tv1 * mv1 + bv * (1.f - mv1);
        wq[r1 + j] = __builtin_convertvector(w1 * 65535.f + 0.5f, u16x4);
        f4 d1 = w1 - xv; s[1] += (double)hsum(d1 * d1);
        f4 tv2 = __builtin_nontemporal_load(&temps[r2 + j]);
        f4 mv2 = __builtin_nontemporal_load(&masks[r2 + j]);
        f4 w2 = tv2 * mv2 + bv * (1.f - mv2);
        wq[r2 + j] = __builtin_convertvector(w2 * 65535.f + 0.5f, u16x4);
        f4 d2 = w2 - xv; s[2] += (double)hsum(d2 * d2);
        f4 tv3 = __builtin_nontemporal_load(&temps[r3 + j]);
        f4 mv3 = __builtin_nontemporal_load(&masks[r3 + j]);
        f4 w3 = tv3 * mv3 + bv * (1.f - mv3);
        wq[r3 + j] = __builtin_convertvector(w3 * 65535.f + 0.5f, u16x4);
        f4 d3 = w3 - xv; s[3] += (double)hsum(d3 * d3);
    }
    blk_reduce4(s);
    if (tid == 0)
        for (int k = 0; k < 4; ++k) err32[b * TP1 + tbase + k] = s[k];
}

// Fused update+screen for step l (slot = l-1):
//  all blocks recompute state_l = update(state_{l-1}, sel) on the fly (identical f32
//  expressions everywhere); screen blocks (rg<36) dot 8 candidate rows x half-pixels
//  against (M,R); the special block (rg==36) persists state_l (ping-pong), emits
//  obj/msk[slot], t0 score and margin accumulator D.
template <bool FIRST>
__global__ __launch_bounds__(256) void k_comb(
    const f8* __restrict__ temps8, const f8* __restrict__ masks8,
    const f8* __restrict__ x8, const u16x8* __restrict__ wq,
    const int* __restrict__ selp,
    const f8* __restrict__ Mold, const f8* __restrict__ Rold,
    f8* __restrict__ Mnew, f8* __restrict__ Rnew,
    double* __restrict__ e16h, double* __restrict__ Dd,
    f8* __restrict__ obj8, f8* __restrict__ msk8, int slot) {
    const int lin = blockIdx.x;
    const int wg = (lin & 7) * BCHUNK + (lin >> 3);
    const int b = wg / RB, rg = wg - b * RB;
    const int tid = threadIdx.x;
    const int sel = selp[b];
    const bool selz = (sel == 0);
    const size_t selrow = selz ? 0 : ((size_t)(b * TT + sel - 1)) * HW8;
    const size_t sb = (size_t)b * HW8;

    if (rg == RB - 1) {   // special: persist state + obj/msk + t0 score + D
        double s = 0.0, dD = 0.0;
        const size_t ob = ((size_t)(b * LL + slot)) * HW8;
        for (int j = tid; j < HW8; j += 256) {
            f8 st_, sm_;
            if (selz) { st_ = (f8)(5.f); sm_ = (f8)(1.f); }
            else      { st_ = temps8[selrow + j]; sm_ = masks8[selrow + j]; }
            f8 Mo, Ro;
            if (FIRST) { Mo = (f8)(1.f); Ro = x8[sb + j]; }
            else       { Mo = Mold[sb + j]; Ro = Rold[sb + j]; }
            f8 m  = Mo * (1.f - sm_);
            f8 rr = Ro - Mo * st_ * sm_;
            Mnew[sb + j] = m;  Rnew[sb + j] = rr;
            obj8[ob + j] = st_; msk8[ob + j] = sm_;
            f8 d0 = m * 5.f - rr;
            s  += (double)hsum8(d0 * d0);
            dD += (double)hsum8(m * (m + fabs8(rr)));
        }
        blk_reduce2(s, dD);
        if (tid == 0) {
            e16h[(size_t)b * TP1] = s;                    // half 0 holds full t0 score
            e16h[(size_t)(BB * TP1) + b * TP1] = 0.0;     // half 1 zero
            Dd[b] = dD;
        }
        return;
    }

    // screen block: 8 rows, half-pixels
    const int h = rg & 1;
    const int tbase = 1 + (rg >> 1) * 8;
    const int hb = h * 1024;                              // f8/u16x8 group offset
    const size_t rowb = ((size_t)(b * TT + tbase - 1)) * HW8 + hb;
    double acc[8] = {0, 0, 0, 0, 0, 0, 0, 0};
    for (int jj = tid; jj < 1024; jj += 256) {
        const int j = hb + jj;
        f8 st_, sm_;
        if (selz) { st_ = (f8)(5.f); sm_ = (f8)(1.f); }
        else      { st_ = temps8[selrow + j]; sm_ = masks8[selrow + j]; }
        f8 Mo, Ro;
        if (FIRST) { Mo = (f8)(1.f); Ro = x8[sb + j]; }
        else       { Mo = Mold[sb + j]; Ro = Rold[sb + j]; }
        f8 m  = Mo * (1.f - sm_);
        f8 rr = Ro - Mo * st_ * sm_;
        f8 ms = m * (1.f / 65535.f);
        #pragma unroll
        for (int k = 0; k < 8; ++k) {
            f8 q = __builtin_convertvector(wq[rowb + (size_t)k * HW8 + jj], f8);
            f8 d = q * ms - rr;
            acc[k] += (double)hsum8(d * d);
        }
    }
    blk_reduce8(acc);
    if (tid == 0) {
        double* dst = e16h + (size_t)h * (BB * TP1) + (size_t)b * TP1 + tbase;
        #pragma unroll
        for (int k = 0; k < 8; ++k) dst[k] = acc[k];
    }
}

// Resolve selection for step l: min (+ sound margin shortlist on screen sums,
// rare exact re-eval vs current state), write selp/ids/used. One block per batch.
template <bool EXACT>
__global__ void k_resolve(const f4* __restrict__ temps, const f4* __restrict__ masks,
                          const f4* __restrict__ bg,
                          const f4* __restrict__ Mst, const f4* __restrict__ Rst,
                          const double* __restrict__ scr, const double* __restrict__ Dd,
                          int* __restrict__ used, int* __restrict__ selp,
                          float* __restrict__ out_ids, int l) {
    const int b = blockIdx.x;
    const int tid = threadIdx.x;
    __shared__ int s_sel, s_cnt;
    __shared__ ull s_mask[3];
    __shared__ double s_e0;
    if (tid < 64) {
        double e0 = 1e301, e1 = 1e301, e2 = 1e301;
        {
            int t0i = tid, t1i = tid + 64, t2i = tid + 128;
            e0 = EXACT ? scr[b * TP1 + t0i]
                       : scr[b * TP1 + t0i] + scr[(size_t)(BB * TP1) + b * TP1 + t0i];
            if (t1i < TP1)
                e1 = EXACT ? scr[b * TP1 + t1i]
                           : scr[b * TP1 + t1i] + scr[(size_t)(BB * TP1) + b * TP1 + t1i];
            if (t2i < TP1)
                e2 = EXACT ? scr[b * TP1 + t2i]
                           : scr[b * TP1 + t2i] + scr[(size_t)(BB * TP1) + b * TP1 + t2i];
            if (!EXACT) {
                if (t0i != 0 && used[b * TP1 + t0i]) e0 = BIGE;
                if (t1i < TP1 && used[b * TP1 + t1i]) e1 = BIGE;
                if (t2i < TP1 && used[b * TP1 + t2i]) e2 = BIGE;
            }
        }
        if (tid == 0) s_e0 = e0;   // t=0 score (exact form)
        double best = e0; int bi = tid;
        if (e1 < best) { best = e1; bi = tid + 64; }
        if (e2 < best) { best = e2; bi = tid + 128; }
        for (int off = 32; off; off >>= 1) {
            double oe = __shfl_down(best, off);
            int    oi = __shfl_down(bi, off);
            if (oe < best || (oe == best && oi < bi)) { best = oe; bi = oi; }
        }
        best = __shfl(best, 0); bi = __shfl(bi, 0);
        if (EXACT) {
            if (tid == 0) { s_sel = bi; s_cnt = 1; }
        } else {
            const double thr = best + (6.0 * EPSQ * Dd[b] + 0.15);
            ull m0 = __ballot(e0 <= thr);
            ull m1 = __ballot(e1 <= thr);
            ull m2 = __ballot(e2 <= thr);
            if (tid == 0) {
                s_mask[0] = m0; s_mask[1] = m1; s_mask[2] = m2;
                s_cnt = __popcll(m0) + __popcll(m1) + __popcll(m2);
                s_sel = bi;
            }
        }
    }
    __syncthreads();
    if (!EXACT && s_cnt > 1) {
        __shared__ double s_beste; __shared__ int s_besti;
        if (tid == 0) { s_beste = 1e301; s_besti = -1; }
        __syncthreads();
        const f4* Mb = Mst + (size_t)b * HW4;
        const f4* Rb = Rst + (size_t)b * HW4;
        for (int t = 0; t < TP1; ++t) {
            if (!((s_mask[t >> 6] >> (t & 63)) & 1ull)) continue;
            double s;
            if (t == 0) {
                s = s_e0;   // exact form already
            } else {
                const size_t row = ((size_t)(b * TT + t - 1)) * HW4;
                double acc = 0.0;
                for (int j = tid; j < HW4; j += 256) {
                    f4 tv = temps[row + j], mv = masks[row + j], bv = bg[j];
                    f4 w = tv * mv + bv * (1.f - mv);
                    f4 d = w * Mb[j] - Rb[j];
                    acc += (double)hsum(d * d);
                }
                s = blk_reduce(acc);
            }
            if (tid == 0 && s < s_beste) { s_beste = s; s_besti = t; }
            __syncthreads();
        }
        if (tid == 0) s_sel = s_besti;
        __syncthreads();
    }
    if (tid == 0) {
        const int sel = s_sel;
        selp[b] = sel;
        out_ids[b * LL + l] = (float)sel;
        if (sel != 0) used[b * TP1 + sel] = 1;
    }
}

// Final: apply sel_5, emit obj/msk slot 5 and recons = (x - R_new) + M_new*bg.
__global__ void k_final(const f8* __restrict__ temps8, const f8* __restrict__ masks8,
                        const f8* __restrict__ x8, const f8* __restrict__ bg8,
                        const int* __restrict__ selp,
                        const f8* __restrict__ Mst8, const f8* __restrict__ Rst8,
                        f8* __restrict__ obj8, f8* __restrict__ msk8,
                        f8* __restrict__ rec8) {
    const int gid = blockIdx.x * 256 + threadIdx.x;   // 32768 f8 groups, 128 blocks
    const int b = gid >> 11, j = gid & (HW8 - 1);
    const int sel = selp[b];
    f8 st_, sm_;
    if (sel == 0) { st_ = (f8)(5.f); sm_ = (f8)(1.f); }
    else {
        size_t rb = ((size_t)(b * TT + sel - 1)) * HW8 + j;
        st_ = temps8[rb]; sm_ = masks8[rb];
    }
    const size_t g = (size_t)b * HW8 + j;
    f8 Mo = Mst8[g], Ro = Rst8[g];
    f8 m  = Mo * (1.f - sm_);
    f8 rr = Ro - Mo * st_ * sm_;
    const size_t ob = ((size_t)(b * LL + (LL - 1))) * HW8 + j;
    obj8[ob] = st_; msk8[ob] = sm_;
    rec8[g] = (x8[g] - rr) + m * bg8[j];
}

// ---------- fallback path (small ws): exact d-form per (b,t), R8-proven ----------
__global__ void k_init0(const f4* __restrict__ x, f4* __restrict__ Mst, f4* __restrict__ Rst,
                        int* __restrict__ used) {
    int gid = blockIdx.x * blockDim.x + threadIdx.x;
    if (gid < BB * TP1) used[gid] = 0;
    if (gid >= BB * HW4) return;
    Mst[gid] = (f4){1.f, 1.f, 1.f, 1.f};
    Rst[gid] = x[gid];
}

__global__ void k_errfb(const f4* __restrict__ temps, const f4* __restrict__ masks,
                        const f4* __restrict__ bg,
                        const f4* __restrict__ Mst, const f4* __restrict__ Rst,
                        const int* __restrict__ used, double* __restrict__ err32) {
    const int lin = blockIdx.x;
    const int wg = (lin & 7) * RCHUNK + (lin >> 3);
    const int b = wg / TP1, t = wg - b * TP1;
    const int tid = threadIdx.x;
    if (t != 0 && used[b * TP1 + t]) {
        if (tid == 0) err32[b * TP1 + t] = BIGE;
        return;
    }
    const f4* Mb = Mst + (size_t)b * HW4;
    const f4* Rb = Rst + (size_t)b * HW4;
    double s = 0.0;
    if (t == 0) {
        for (int j = tid; j < HW4; j += 256) {
            f4 d = Mb[j] * 5.f - Rb[j];
            s += (double)hsum(d * d);
        }
    } else {
        const size_t row = ((size_t)(b * TT + t - 1)) * HW4;
        for (int j = tid; j < HW4; j += 256) {
            f4 tv = temps[row + j], mv = masks[row + j], bv = bg[j];
            f4 w = tv * mv + bv * (1.f - mv);
            f4 d = w * Mb[j] - Rb[j];
            s += (double)hsum(d * d);
        }
    }
    double tot = blk_reduce(s);
    if (tid == 0) err32[b * TP1 + t] = tot;
}

template <bool FIRST, bool LAST>
__global__ void k_updfb(const f4* __restrict__ temps, const f4* __restrict__ masks,
                        const f4* __restrict__ x, const f4* __restrict__ bg,
                        const double* __restrict__ err,
                        int* __restrict__ used, f4* __restrict__ Mst, f4* __restrict__ Rst,
                        f4* __restrict__ out_obj, f4* __restrict__ out_msk,
                        f4* __restrict__ out_rec, float* __restrict__ out_ids, int l) {
    const int tid = threadIdx.x;
    const int gid = blockIdx.x * 256 + tid;
    const int b = gid >> 12;
    const int p = gid & (HW4 - 1);
    __shared__ int ssel;
    if (tid < 64) {
        double best = 1e301; int bi = TP1;
        for (int t = tid; t < TP1; t += 64) {
            double e = err[b * TP1 + t];
            if (e < best) { best = e; bi = t; }
        }
        for (int off = 32; off; off >>= 1) {
            double oe = __shfl_down(best, off);
            int    oi = __shfl_down(bi, off);
            if (oe < best || (oe == best && oi < bi)) { best = oe; bi = oi; }
        }
        if (tid == 0) ssel = bi;
    }
    __syncthreads();
    const int id = ssel;
    f4 st, sm_;
    if (id == 0) { st = (f4){5.f,5.f,5.f,5.f}; sm_ = (f4){1.f,1.f,1.f,1.f}; }
    else {
        size_t base = ((size_t)(b * TT + id - 1)) * HW4 + p;
        st = temps[base]; sm_ = masks[base];
    }
    f4 xv = x[gid];
    f4 a, mp;
    if (FIRST) { a = (f4){0.f,0.f,0.f,0.f}; mp = (f4){1.f,1.f,1.f,1.f}; }
    else       { mp = Mst[gid]; a = xv - Rst[gid]; }
    a = a + mp * st * sm_;
    mp = mp * (1.f - sm_);
    const size_t ob = ((size_t)(b * LL + l)) * HW4 + p;
    out_obj[ob] = st;
    out_msk[ob] = sm_;
    if (LAST) {
        out_rec[gid] = a + mp * bg[p];
    } else {
        Mst[gid] = mp;
        Rst[gid] = xv - a;
    }
    if ((blockIdx.x & 15) == 0 && tid == 0) {
        if (id != 0) used[b * TP1 + id] = 1;
        out_ids[b * LL + l] = (float)id;
    }
}

extern "C" void kernel_launch(void* const* d_in, const int* in_sizes, int n_in,
                              void* d_out, int out_size, void* d_ws, size_t ws_size,
                              hipStream_t stream) {
    const f4* x     = (const f4*)d_in[0];
    const f4* temps = (const f4*)d_in[1];
    const f4* masks = (const f4*)d_in[2];
    const f4* bg    = (const f4*)d_in[3];

    float* out      = (float*)d_out;
    f4*    out_rec  = (f4*)out;                           // B*HW
    f4*    out_obj  = (f4*)(out + 262144);                // B*L*HW
    f4*    out_msk  = (f4*)(out + 262144 + 1572864);      // B*L*HW
    float* out_ids  = out + 262144 + 2 * 1572864;         // B*L

    char* ws = (char*)d_ws;
    f4*     M0s   = (f4*)(ws + OFF_M0);
    f4*     R0s   = (f4*)(ws + OFF_R0);
    f4*     M1s   = (f4*)(ws + OFF_M1);
    f4*     R1s   = (f4*)(ws + OFF_R1);
    double* err32 = (double*)(ws + OFF_E32);
    double* e16h  = (double*)(ws + OFF_E16H);
    double* Dd    = (double*)(ws + OFF_D);
    int*    used  = (int*)(ws + OFF_USED);
    int*    selp  = (int*)(ws + OFF_SEL);
    u16x4*  wq    = (u16x4*)(ws + OFF_WQ);

    const bool full = (ws_size >= WS_FULL);

    if (full) {
        f4* Mb[2] = {M0s, M1s};
        f4* Rb[2] = {R0s, R1s};
        k_build<<<NBLK, 256, 0, stream>>>(temps, masks, bg, x, wq, err32, used);
        k_resolve<true><<<BB, 256, 0, stream>>>(temps, masks, bg, M0s, R0s,
                                                err32, Dd, used, selp, out_ids, 0);
        for (int l = 1; l < LL; ++l) {
            const int cur = l & 1, prv = cur ^ 1;
            if (l == 1)
                k_comb<true><<<NBLK, 256, 0, stream>>>(
                    (const f8*)temps, (const f8*)masks, (const f8*)x, (const u16x8*)wq,
                    selp, (const f8*)Mb[prv], (const f8*)Rb[prv],
                    (f8*)Mb[cur], (f8*)Rb[cur], e16h, Dd,
                    (f8*)out_obj, (f8*)out_msk, l - 1);
            else
                k_comb<false><<<NBLK, 256, 0, stream>>>(
                    (const f8*)temps, (const f8*)masks, (const f8*)x, (const u16x8*)wq,
                    selp, (const f8*)Mb[prv], (const f8*)Rb[prv],
                    (f8*)Mb[cur], (f8*)Rb[cur], e16h, Dd,
                    (f8*)out_obj, (f8*)out_msk, l - 1);
            k_resolve<false><<<BB, 256, 0, stream>>>(temps, masks, bg, Mb[cur], Rb[cur],
                                                     e16h, Dd, used, selp, out_ids, l);
        }
        // state_5 lives in buffer 1 (l=5 -> cur=1)
        k_final<<<128, 256, 0, stream>>>((const f8*)temps, (const f8*)masks,
                                         (const f8*)x, (const f8*)bg, selp,
                                         (const f8*)M1s, (const f8*)R1s,
                                         (f8*)out_obj, (f8*)out_msk, (f8*)out_rec);
    } else {
        k_init0<<<(BB * HW4 + 255) / 256, 256, 0, stream>>>(x, M0s, R0s, used);
        for (int l = 0; l < LL; ++l) {
            k_errfb<<<BB * TP1, 256, 0, stream>>>(temps, masks, bg, M0s, R0s, used, err32);
            if (l == 0)
                k_updfb<true, false><<<256, 256, 0, stream>>>(temps, masks, x, bg, err32, used,
                                                              M0s, R0s, out_obj, out_msk, out_rec, out_ids, l);
            else if (l == LL - 1)
                k_updfb<false, true><<<256, 256, 0, stream>>>(temps, masks, x, bg, err32, used,
                                                              M0s, R0s, out_obj, out_msk, out_rec, out_ids, l);
            else
                k_updfb<false, false><<<256, 256, 0, stream>>>(temps, masks, x, bg, err32, used,
                                                               M0s, R0s, out_obj, out_msk, out_rec, out_ids, l);
        }
    }
}

// Round 11
// 362.849 us; speedup vs baseline: 1.2250x; 1.0509x over previous
//
#include <hip/hip_runtime.h>
#include <math.h>

#define BB 16
#define TT 144
#define TP1 145
#define HW4 4096   // f4 groups per image
#define HW8 2048   // f8/u16x8 groups per image
#define LL 6
#define BIGE 1e30
#define EPSQ 7.62951e-6  // 0.5/65535 quantization bound on w in [0,1]
#define RB 37            // 36 blocks of 4 t-rows + 1 special block per batch
#define NBLK (BB * RB)   // 592
#define BCHUNK 74        // 592/8 XCDs (bijective)
#define RCHUNK 290       // 2320/8 (fallback)

typedef float          f4    __attribute__((ext_vector_type(4)));
typedef float          f8    __attribute__((ext_vector_type(8)));
typedef unsigned short u16x4 __attribute__((ext_vector_type(4)));
typedef unsigned short u16x8 __attribute__((ext_vector_type(8)));
typedef unsigned long long ull;

// ---- workspace layout (bytes) ----
// State streams: Ms = M*(1/65535), R = x - A  (reconstruct M = 65535*Ms, A = x - R)
static const size_t OFF_MS   = 0;                   // B*HW f32 (1 MB)
static const size_t OFF_R    = 1u << 20;            // B*HW f32
static const size_t OFF_E32  = 2u << 20;            // B*145 f64 (build exact scores)
static const size_t OFF_E16  = (2u << 20) + 32768;  // B*145 f64 (screen scores)
static const size_t OFF_D    = (2u << 20) + 65536;  // B f64
static const size_t OFF_USED = (2u << 20) + 81920;  // B*145 i32
static const size_t OFF_SEL  = (2u << 20) + 98304;  // B i32
static const size_t OFF_WQ   = 3u << 20;            // B*T*HW u16 = 75,497,472
static const size_t WS_FULL  = OFF_WQ + 75497472ull;

__device__ __forceinline__ float hsum(f4 v) { return ((v.x + v.y) + v.z) + v.w; }
__device__ __forceinline__ float hsum8(f8 v) {
    return (((v.s0 + v.s1) + (v.s2 + v.s3)) + ((v.s4 + v.s5) + (v.s6 + v.s7)));
}
__device__ __forceinline__ f8 fabs8(f8 v) {
    f8 o;
    o.s0 = __builtin_fabsf(v.s0); o.s1 = __builtin_fabsf(v.s1);
    o.s2 = __builtin_fabsf(v.s2); o.s3 = __builtin_fabsf(v.s3);
    o.s4 = __builtin_fabsf(v.s4); o.s5 = __builtin_fabsf(v.s5);
    o.s6 = __builtin_fabsf(v.s6); o.s7 = __builtin_fabsf(v.s7);
    return o;
}

__device__ __forceinline__ double blk_reduce(double s) {
    for (int off = 32; off; off >>= 1) s += __shfl_down(s, off);
    __shared__ double smr[4];
    if ((threadIdx.x & 63) == 0) smr[threadIdx.x >> 6] = s;
    __syncthreads();
    double r = smr[0] + smr[1] + smr[2] + smr[3];
    __syncthreads();
    return r;
}

__device__ __forceinline__ void blk_reduce2(double& a, double& b) {
    for (int off = 32; off; off >>= 1) { a += __shfl_down(a, off); b += __shfl_down(b, off); }
    __shared__ double sa[4], sb[4];
    if ((threadIdx.x & 63) == 0) { sa[threadIdx.x >> 6] = a; sb[threadIdx.x >> 6] = b; }
    __syncthreads();
    a = sa[0] + sa[1] + sa[2] + sa[3];
    b = sb[0] + sb[1] + sb[2] + sb[3];
    __syncthreads();
}

__device__ __forceinline__ void blk_reduce4(double s[4]) {
    for (int off = 32; off; off >>= 1) {
        s[0] += __shfl_down(s[0], off); s[1] += __shfl_down(s[1], off);
        s[2] += __shfl_down(s[2], off); s[3] += __shfl_down(s[3], off);
    }
    __shared__ double sm4[4][4];
    const int wv = threadIdx.x >> 6;
    if ((threadIdx.x & 63) == 0) {
        sm4[wv][0] = s[0]; sm4[wv][1] = s[1]; sm4[wv][2] = s[2]; sm4[wv][3] = s[3];
    }
    __syncthreads();
    for (int k = 0; k < 4; ++k) s[k] = sm4[0][k] + sm4[1][k] + sm4[2][k] + sm4[3][k];
}

// ---- R8-proven build: wq = u16(round(65535*w)), w = t*m + bg*(1-m); exact step-0
// scores; zero used[]. temps/masks read-once -> non-temporal. 4 rows/block. ----
__global__ void k_build(const f4* __restrict__ temps, const f4* __restrict__ masks,
                        const f4* __restrict__ bg, const f4* __restrict__ x,
                        u16x4* __restrict__ wq, double* __restrict__ err32,
                        int* __restrict__ used) {
    const int lin = blockIdx.x;
    const int wg = (lin & 7) * BCHUNK + (lin >> 3);   // XCD-chunked bijective swizzle
    const int b = wg / RB, rg = wg - b * RB;
    const int tid = threadIdx.x;
    const f4* xb = x + (size_t)b * HW4;
    if (rg == RB - 1) {   // t = 0: w = 5 exactly
        if (tid < TP1) used[b * TP1 + tid] = 0;
        double s = 0.0;
        for (int j = tid; j < HW4; j += 256) {
            f4 d = 5.f - xb[j];
            s += (double)hsum(d * d);
        }
        double tot = blk_reduce(s);
        if (tid == 0) err32[b * TP1 + 0] = tot;
        return;
    }
    const int tbase = 1 + rg * 4;
    const size_t r0 = ((size_t)(b * TT + tbase - 1)) * HW4;
    const size_t r1 = r0 + HW4, r2 = r1 + HW4, r3 = r2 + HW4;
    double s[4] = {0.0, 0.0, 0.0, 0.0};
    #pragma unroll 2
    for (int j = tid; j < HW4; j += 256) {
        f4 bv = bg[j], xv = xb[j];
        f4 tv0 = __builtin_nontemporal_load(&temps[r0 + j]);
        f4 mv0 = __builtin_nontemporal_load(&masks[r0 + j]);
        f4 w0 = tv0 * mv0 + bv * (1.f - mv0);
        wq[r0 + j] = __builtin_convertvector(w0 * 65535.f + 0.5f, u16x4);
        f4 d0 = w0 - xv; s[0] += (double)hsum(d0 * d0);
        f4 tv1 = __builtin_nontemporal_load(&temps[r1 + j]);
        f4 mv1 = __builtin_nontemporal_load(&masks[r1 + j]);
        f4 w1 = tv1 * mv1 + bv * (1.f - mv1);
        wq[r1 + j] = __builtin_convertvector(w1 * 65535.f + 0.5f, u16x4);
        f4 d1 = w1 - xv; s[1] += (double)hsum(d1 * d1);
        f4 tv2 = __builtin_nontemporal_load(&temps[r2 + j]);
        f4 mv2 = __builtin_nontemporal_load(&masks[r2 + j]);
        f4 w2 = tv2 * mv2 + bv * (1.f - mv2);
        wq[r2 + j] = __builtin_convertvector(w2 * 65535.f + 0.5f, u16x4);
        f4 d2 = w2 - xv; s[2] += (double)hsum(d2 * d2);
        f4 tv3 = __builtin_nontemporal_load(&temps[r3 + j]);
        f4 mv3 = __builtin_nontemporal_load(&masks[r3 + j]);
        f4 w3 = tv3 * mv3 + bv * (1.f - mv3);
        wq[r3 + j] = __builtin_convertvector(w3 * 65535.f + 0.5f, u16x4);
        f4 d3 = w3 - xv; s[3] += (double)hsum(d3 * d3);
    }
    blk_reduce4(s);
    if (tid == 0)
        for (int k = 0; k < 4; ++k) err32[b * TP1 + tbase + k] = s[k];
}

// ---- R8-proven screen: 4 rows/block, d = fma(q, Ms, -r), raw scores (mask in resolve).
// t0 block: exact t=0 score + D = sum(M*(M+|r|)). ----
__global__ void k_errs(const u16x8* __restrict__ wq,
                       const f8* __restrict__ Ms, const f8* __restrict__ R,
                       double* __restrict__ err16, double* __restrict__ Dd) {
    const int lin = blockIdx.x;
    const int wg = (lin & 7) * BCHUNK + (lin >> 3);
    const int b = wg / RB, rg = wg - b * RB;
    const int tid = threadIdx.x;
    const f8* msb = Ms + (size_t)b * HW8;
    const f8* rb  = R  + (size_t)b * HW8;
    if (rg == RB - 1) {
        double s = 0.0, d = 0.0;
        for (int j = tid; j < HW8; j += 256) {
            f8 ms = msb[j], rr = rb[j];
            f8 M = ms * 65535.f;
            f8 dd = M * 5.f - rr;
            s += (double)hsum8(dd * dd);
            d += (double)hsum8(M * (M + fabs8(rr)));
        }
        blk_reduce2(s, d);
        if (tid == 0) { err16[b * TP1 + 0] = s; Dd[b] = d; }
        return;
    }
    const int tbase = 1 + rg * 4;
    const size_t r0 = ((size_t)(b * TT + tbase - 1)) * HW8;
    const size_t r1 = r0 + HW8, r2 = r1 + HW8, r3 = r2 + HW8;
    double s[4] = {0.0, 0.0, 0.0, 0.0};
    #pragma unroll 2
    for (int j = tid; j < HW8; j += 256) {
        f8 ms = msb[j], rr = rb[j];
        f8 q0 = __builtin_convertvector(wq[r0 + j], f8);
        f8 d0 = q0 * ms - rr; s[0] += (double)hsum8(d0 * d0);
        f8 q1 = __builtin_convertvector(wq[r1 + j], f8);
        f8 d1 = q1 * ms - rr; s[1] += (double)hsum8(d1 * d1);
        f8 q2 = __builtin_convertvector(wq[r2 + j], f8);
        f8 d2 = q2 * ms - rr; s[2] += (double)hsum8(d2 * d2);
        f8 q3 = __builtin_convertvector(wq[r3 + j], f8);
        f8 d3 = q3 * ms - rr; s[3] += (double)hsum8(d3 * d3);
    }
    blk_reduce4(s);
    if (tid == 0)
        for (int k = 0; k < 4; ++k) err16[b * TP1 + tbase + k] = s[k];
}

// ---- R9/R10-proven resolve: one block per batch. Min over (used-masked) scores,
// sound-margin shortlist, rare exact f32 re-eval; writes selp/ids/used. ----
template <bool EXACT>
__global__ void k_resolve(const f4* __restrict__ temps, const f4* __restrict__ masks,
                          const f4* __restrict__ bg,
                          const f4* __restrict__ Ms4, const f4* __restrict__ R4,
                          const double* __restrict__ scr, const double* __restrict__ Dd,
                          int* __restrict__ used, int* __restrict__ selp,
                          float* __restrict__ out_ids, int l) {
    const int b = blockIdx.x;
    const int tid = threadIdx.x;
    __shared__ int s_sel, s_cnt;
    __shared__ ull s_mask[3];
    __shared__ double s_e0;
    if (tid < 64) {
        double e0 = scr[b * TP1 + tid];
        double e1 = (tid + 64 < TP1) ? scr[b * TP1 + tid + 64] : 1e301;
        double e2 = (tid + 128 < TP1) ? scr[b * TP1 + tid + 128] : 1e301;
        if (!EXACT) {
            if (tid != 0 && used[b * TP1 + tid]) e0 = BIGE;
            if (tid + 64 < TP1 && used[b * TP1 + tid + 64]) e1 = BIGE;
            if (tid + 128 < TP1 && used[b * TP1 + tid + 128]) e2 = BIGE;
        }
        if (tid == 0) s_e0 = e0;
        double best = e0; int bi = tid;
        if (e1 < best) { best = e1; bi = tid + 64; }
        if (e2 < best) { best = e2; bi = tid + 128; }
        for (int off = 32; off; off >>= 1) {
            double oe = __shfl_down(best, off);
            int    oi = __shfl_down(bi, off);
            if (oe < best || (oe == best && oi < bi)) { best = oe; bi = oi; }
        }
        best = __shfl(best, 0); bi = __shfl(bi, 0);
        if (EXACT) {
            if (tid == 0) { s_sel = bi; s_cnt = 1; }
        } else {
            const double thr = best + (6.0 * EPSQ * Dd[b] + 0.15);
            ull m0 = __ballot(e0 <= thr);
            ull m1 = __ballot(e1 <= thr);
            ull m2 = __ballot(e2 <= thr);
            if (tid == 0) {
                s_mask[0] = m0; s_mask[1] = m1; s_mask[2] = m2;
                s_cnt = __popcll(m0) + __popcll(m1) + __popcll(m2);
                s_sel = bi;   // screen argmin (final if singleton)
            }
        }
    }
    __syncthreads();
    if (!EXACT && s_cnt > 1) {
        // rare: exact f32 evals of shortlist, ascending t, strict < (first-index ties)
        __shared__ double s_beste; __shared__ int s_besti;
        if (tid == 0) { s_beste = 1e301; s_besti = -1; }
        __syncthreads();
        const f4* Mb = Ms4 + (size_t)b * HW4;
        const f4* Rb = R4  + (size_t)b * HW4;
        for (int t = 0; t < TP1; ++t) {
            if (!((s_mask[t >> 6] >> (t & 63)) & 1ull)) continue;
            double s;
            if (t == 0) {
                s = s_e0;   // exact-form already
            } else {
                const size_t row = ((size_t)(b * TT + t - 1)) * HW4;
                double acc = 0.0;
                for (int j = tid; j < HW4; j += 256) {
                    f4 tv = temps[row + j], mv = masks[row + j], bv = bg[j];
                    f4 w = tv * mv + bv * (1.f - mv);
                    f4 M = Mb[j] * 65535.f;
                    f4 d = w * M - Rb[j];
                    acc += (double)hsum(d * d);
                }
                s = blk_reduce(acc);
            }
            if (tid == 0 && s < s_beste) { s_beste = s; s_besti = t; }
            __syncthreads();
        }
        if (tid == 0) s_sel = s_besti;
        __syncthreads();
    }
    if (tid == 0) {
        const int sel = s_sel;
        selp[b] = sel;
        out_ids[b * LL + l] = (float)sel;
        if (sel != 0) used[b * TP1 + sel] = 1;
    }
}

// ---- R8-proven update, minus the argmin scan (reads selp). LAST emits recons. ----
template <bool FIRST, bool LAST>
__global__ void k_upd(const f4* __restrict__ temps, const f4* __restrict__ masks,
                      const f4* __restrict__ x, const f4* __restrict__ bg,
                      const int* __restrict__ selp,
                      f4* __restrict__ Ms4, f4* __restrict__ R4,
                      f4* __restrict__ out_obj, f4* __restrict__ out_msk,
                      f4* __restrict__ out_rec, int l) {
    const int lin = blockIdx.x;
    const int wg = (lin & 7) * 32 + (lin >> 3);    // 256 = 8*32 bijective
    const int tid = threadIdx.x;
    const int gid = wg * 256 + tid;
    const int b = gid >> 12;
    const int p = gid & (HW4 - 1);
    const int id = selp[b];
    f4 st, sm_;
    if (id == 0) { st = (f4){5.f,5.f,5.f,5.f}; sm_ = (f4){1.f,1.f,1.f,1.f}; }
    else {
        size_t base = ((size_t)(b * TT + id - 1)) * HW4 + p;
        st = temps[base]; sm_ = masks[base];
    }
    f4 xv = x[gid];
    f4 a, mp;
    if (FIRST) { a = (f4){0.f,0.f,0.f,0.f}; mp = (f4){1.f,1.f,1.f,1.f}; }
    else       { mp = Ms4[gid] * 65535.f; a = xv - R4[gid]; }
    a = a + mp * st * sm_;
    mp = mp * (1.f - sm_);
    const size_t ob = ((size_t)(b * LL + l)) * HW4 + p;
    out_obj[ob] = st;
    out_msk[ob] = sm_;
    if (LAST) {
        out_rec[gid] = a + mp * bg[p];
    } else {
        Ms4[gid] = mp * (1.f / 65535.f);
        R4[gid]  = xv - a;
    }
}

// ---------- fallback path (small ws): R8-proven exact d-form ----------
__global__ void k_init0(const f4* __restrict__ x, f4* __restrict__ Ms4, f4* __restrict__ R4,
                        int* __restrict__ used) {
    int gid = blockIdx.x * blockDim.x + threadIdx.x;
    if (gid < BB * TP1) used[gid] = 0;
    if (gid >= BB * HW4) return;
    float msv = (float)(1.0 / 65535.0);
    Ms4[gid] = (f4){msv, msv, msv, msv};
    R4[gid] = x[gid];
}

__global__ void k_errfb(const f4* __restrict__ temps, const f4* __restrict__ masks,
                        const f4* __restrict__ bg,
                        const f4* __restrict__ Ms4, const f4* __restrict__ R4,
                        const int* __restrict__ used, double* __restrict__ err32) {
    const int lin = blockIdx.x;
    const int wg = (lin & 7) * RCHUNK + (lin >> 3);
    const int b = wg / TP1, t = wg - b * TP1;
    const int tid = threadIdx.x;
    if (t != 0 && used[b * TP1 + t]) {
        if (tid == 0) err32[b * TP1 + t] = BIGE;
        return;
    }
    const f4* msb = Ms4 + (size_t)b * HW4;
    const f4* rb  = R4  + (size_t)b * HW4;
    double s = 0.0;
    if (t == 0) {
        for (int j = tid; j < HW4; j += 256) {
            f4 M = msb[j] * 65535.f;
            f4 d = M * 5.f - rb[j];
            s += (double)hsum(d * d);
        }
    } else {
        const size_t row = ((size_t)(b * TT + t - 1)) * HW4;
        for (int j = tid; j < HW4; j += 256) {
            f4 tv = temps[row + j], mv = masks[row + j], bv = bg[j];
            f4 w = tv * mv + bv * (1.f - mv);
            f4 M = msb[j] * 65535.f;
            f4 d = w * M - rb[j];
            s += (double)hsum(d * d);
        }
    }
    double tot = blk_reduce(s);
    if (tid == 0) err32[b * TP1 + t] = tot;
}

template <bool FIRST, bool LAST>
__global__ void k_updfb(const f4* __restrict__ temps, const f4* __restrict__ masks,
                        const f4* __restrict__ x, const f4* __restrict__ bg,
                        const double* __restrict__ err,
                        int* __restrict__ used, f4* __restrict__ Ms4, f4* __restrict__ R4,
                        f4* __restrict__ out_obj, f4* __restrict__ out_msk,
                        f4* __restrict__ out_rec, float* __restrict__ out_ids, int l) {
    const int tid = threadIdx.x;
    const int gid = blockIdx.x * 256 + tid;
    const int b = gid >> 12;
    const int p = gid & (HW4 - 1);
    __shared__ int ssel;
    if (tid < 64) {
        double best = 1e301; int bi = TP1;
        for (int t = tid; t < TP1; t += 64) {
            double e = err[b * TP1 + t];
            if (e < best) { best = e; bi = t; }
        }
        for (int off = 32; off; off >>= 1) {
            double oe = __shfl_down(best, off);
            int    oi = __shfl_down(bi, off);
            if (oe < best || (oe == best && oi < bi)) { best = oe; bi = oi; }
        }
        if (tid == 0) ssel = bi;
    }
    __syncthreads();
    const int id = ssel;
    f4 st, sm_;
    if (id == 0) { st = (f4){5.f,5.f,5.f,5.f}; sm_ = (f4){1.f,1.f,1.f,1.f}; }
    else {
        size_t base = ((size_t)(b * TT + id - 1)) * HW4 + p;
        st = temps[base]; sm_ = masks[base];
    }
    f4 xv = x[gid];
    f4 a, mp;
    if (FIRST) { a = (f4){0.f,0.f,0.f,0.f}; mp = (f4){1.f,1.f,1.f,1.f}; }
    else       { mp = Ms4[gid] * 65535.f; a = xv - R4[gid]; }
    a = a + mp * st * sm_;
    mp = mp * (1.f - sm_);
    const size_t ob = ((size_t)(b * LL + l)) * HW4 + p;
    out_obj[ob] = st;
    out_msk[ob] = sm_;
    if (LAST) {
        out_rec[gid] = a + mp * bg[p];
    } else {
        Ms4[gid] = mp * (1.f / 65535.f);
        R4[gid]  = xv - a;
    }
    if ((blockIdx.x & 15) == 0 && tid == 0) {
        if (id != 0) used[b * TP1 + id] = 1;
        out_ids[b * LL + l] = (float)id;
    }
}

extern "C" void kernel_launch(void* const* d_in, const int* in_sizes, int n_in,
                              void* d_out, int out_size, void* d_ws, size_t ws_size,
                              hipStream_t stream) {
    const f4* x     = (const f4*)d_in[0];
    const f4* temps = (const f4*)d_in[1];
    const f4* masks = (const f4*)d_in[2];
    const f4* bg    = (const f4*)d_in[3];

    float* out      = (float*)d_out;
    f4*    out_rec  = (f4*)out;                           // B*HW
    f4*    out_obj  = (f4*)(out + 262144);                // B*L*HW
    f4*    out_msk  = (f4*)(out + 262144 + 1572864);      // B*L*HW
    float* out_ids  = out + 262144 + 2 * 1572864;         // B*L

    char* ws = (char*)d_ws;
    f4*     Ms4   = (f4*)(ws + OFF_MS);
    f4*     R4    = (f4*)(ws + OFF_R);
    double* err32 = (double*)(ws + OFF_E32);
    double* err16 = (double*)(ws + OFF_E16);
    double* Dd    = (double*)(ws + OFF_D);
    int*    used  = (int*)(ws + OFF_USED);
    int*    selp  = (int*)(ws + OFF_SEL);
    u16x4*  wq    = (u16x4*)(ws + OFF_WQ);

    const bool full = (ws_size >= WS_FULL);

    if (full) {
        k_build<<<NBLK, 256, 0, stream>>>(temps, masks, bg, x, wq, err32, used);
        k_resolve<true><<<BB, 256, 0, stream>>>(temps, masks, bg, Ms4, R4,
                                                err32, Dd, used, selp, out_ids, 0);
        k_upd<true, false><<<256, 256, 0, stream>>>(temps, masks, x, bg, selp,
                                                    Ms4, R4, out_obj, out_msk, out_rec, 0);
        for (int l = 1; l < LL; ++l) {
            k_errs<<<NBLK, 256, 0, stream>>>((const u16x8*)wq, (const f8*)Ms4, (const f8*)R4,
                                             err16, Dd);
            k_resolve<false><<<BB, 256, 0, stream>>>(temps, masks, bg, Ms4, R4,
                                                     err16, Dd, used, selp, out_ids, l);
            if (l < LL - 1)
                k_upd<false, false><<<256, 256, 0, stream>>>(temps, masks, x, bg, selp,
                                                             Ms4, R4, out_obj, out_msk, out_rec, l);
            else
                k_upd<false, true><<<256, 256, 0, stream>>>(temps, masks, x, bg, selp,
                                                            Ms4, R4, out_obj, out_msk, out_rec, l);
        }
    } else {
        k_init0<<<(BB * HW4 + 255) / 256, 256, 0, stream>>>(x, Ms4, R4, used);
        for (int l = 0; l < LL; ++l) {
            k_errfb<<<BB * TP1, 256, 0, stream>>>(temps, masks, bg, Ms4, R4, used, err32);
            if (l == 0)
                k_updfb<true, false><<<256, 256, 0, stream>>>(temps, masks, x, bg, err32, used,
                                                              Ms4, R4, out_obj, out_msk, out_rec, out_ids, l);
            else if (l == LL - 1)
                k_updfb<false, true><<<256, 256, 0, stream>>>(temps, masks, x, bg, err32, used,
                                                              Ms4, R4, out_obj, out_msk, out_rec, out_ids, l);
            else
                k_updfb<false, false><<<256, 256, 0, stream>>>(temps, masks, x, bg, err32, used,
                                                               Ms4, R4, out_obj, out_msk, out_rec, out_ids, l);
        }
    }
}

// Round 12
// 239.942 us; speedup vs baseline: 1.8525x; 1.5122x over previous
//
#include <hip/hip_runtime.h>
#include <math.h>

#define BB 16
#define TT 144
#define TP1 145
#define HW4 4096   // f4 groups per image
#define HW8 2048   // f8/u16x8 groups per image
#define LL 6
#define BIGE 1e30
#define EPSQ 7.62951e-6  // 0.5/65535 quantization abs error bound on w in [0,1]
#define RB 37            // 36 blocks of 4 t-rows + 1 special (t=0/D) block per batch
#define NBLK (BB * RB)   // 592
#define BCHUNK 74        // 592/8 XCDs (bijective)
#define RCHUNK 290       // 2320/8

typedef float          f4    __attribute__((ext_vector_type(4)));
typedef float          f8    __attribute__((ext_vector_type(8)));
typedef unsigned short u16x4 __attribute__((ext_vector_type(4)));
typedef unsigned short u16x8 __attribute__((ext_vector_type(8)));

// ---- workspace layout (bytes) ----
// State streams: Ms = M*(1/65535), r = x - A  (M, A reconstructed: M=65535*Ms, A=x-r)
static const size_t OFF_MS   = 0;                   // B*HW f32 (1 MB)
static const size_t OFF_R    = 1u << 20;            // B*HW f32
static const size_t OFF_E32  = 2u << 20;            // B*145 f64 (exact/refined scores)
static const size_t OFF_E16  = (2u << 20) + 32768;  // B*145 f64 (screen scores)
static const size_t OFF_D    = (2u << 20) + 65536;  // B f64 (margin accumulator)
static const size_t OFF_USED = (2u << 20) + 81920;  // B*145 i32
static const size_t OFF_WQ   = 3u << 20;            // B*T*HW u16 = 75,497,472
static const size_t WS_FULL  = OFF_WQ + 75497472ull;

__device__ __forceinline__ float hsum(f4 v) { return ((v.x + v.y) + v.z) + v.w; }
__device__ __forceinline__ float hsum8(f8 v) {
    return (((v.s0 + v.s1) + (v.s2 + v.s3)) + ((v.s4 + v.s5) + (v.s6 + v.s7)));
}
__device__ __forceinline__ f8 fabs8(f8 v) {
    f8 o;
    o.s0 = __builtin_fabsf(v.s0); o.s1 = __builtin_fabsf(v.s1);
    o.s2 = __builtin_fabsf(v.s2); o.s3 = __builtin_fabsf(v.s3);
    o.s4 = __builtin_fabsf(v.s4); o.s5 = __builtin_fabsf(v.s5);
    o.s6 = __builtin_fabsf(v.s6); o.s7 = __builtin_fabsf(v.s7);
    return o;
}

__device__ __forceinline__ double blk_reduce(double s) {
    for (int off = 32; off; off >>= 1) s += __shfl_down(s, off);
    __shared__ double smr[4];
    if ((threadIdx.x & 63) == 0) smr[threadIdx.x >> 6] = s;
    __syncthreads();
    return smr[0] + smr[1] + smr[2] + smr[3];
}

__device__ __forceinline__ void blk_reduce2(double& a, double& b) {
    for (int off = 32; off; off >>= 1) { a += __shfl_down(a, off); b += __shfl_down(b, off); }
    __shared__ double sa[4], sb[4];
    if ((threadIdx.x & 63) == 0) { sa[threadIdx.x >> 6] = a; sb[threadIdx.x >> 6] = b; }
    __syncthreads();
    a = sa[0] + sa[1] + sa[2] + sa[3];
    b = sb[0] + sb[1] + sb[2] + sb[3];
}

__device__ __forceinline__ void blk_reduce4(double s[4]) {
    for (int off = 32; off; off >>= 1) {
        s[0] += __shfl_down(s[0], off); s[1] += __shfl_down(s[1], off);
        s[2] += __shfl_down(s[2], off); s[3] += __shfl_down(s[3], off);
    }
    __shared__ double sm4[4][4];
    const int wv = threadIdx.x >> 6;
    if ((threadIdx.x & 63) == 0) {
        sm4[wv][0] = s[0]; sm4[wv][1] = s[1]; sm4[wv][2] = s[2]; sm4[wv][3] = s[3];
    }
    __syncthreads();
    for (int k = 0; k < 4; ++k) s[k] = sm4[0][k] + sm4[1][k] + sm4[2][k] + sm4[3][k];
}

// Build wq = u16(round(65535*w)), w = t*m + bg*(1-m), 4 t-rows per block
// (cuts x/bg L2 broadcast 4x); exact step-0 scores err32 = sum((w-x)^2); zero used[].
__global__ void k_build(const f4* __restrict__ temps, const f4* __restrict__ masks,
                        const f4* __restrict__ bg, const f4* __restrict__ x,
                        u16x4* __restrict__ wq, double* __restrict__ err32,
                        int* __restrict__ used) {
    const int lin = blockIdx.x;
    const int wg = (lin & 7) * BCHUNK + (lin >> 3);   // XCD-chunked bijective swizzle
    const int b = wg / RB, rg = wg - b * RB;
    const int tid = threadIdx.x;
    const f4* xb = x + (size_t)b * HW4;
    if (rg == RB - 1) {   // t = 0: w = 5 exactly
        if (tid < TP1) used[b * TP1 + tid] = 0;
        double s = 0.0;
        for (int j = tid; j < HW4; j += 256) {
            f4 d = 5.f - xb[j];
            s += (double)hsum(d * d);
        }
        double tot = blk_reduce(s);
        if (tid == 0) err32[b * TP1 + 0] = tot;
        return;
    }
    const int tbase = 1 + rg * 4;
    const size_t r0 = ((size_t)(b * TT + tbase - 1)) * HW4;
    const size_t r1 = r0 + HW4, r2 = r1 + HW4, r3 = r2 + HW4;
    double s[4] = {0.0, 0.0, 0.0, 0.0};
    #pragma unroll 2
    for (int j = tid; j < HW4; j += 256) {
        f4 bv = bg[j], xv = xb[j];
        f4 tv0 = __builtin_nontemporal_load(&temps[r0 + j]);
        f4 mv0 = __builtin_nontemporal_load(&masks[r0 + j]);
        f4 w0 = tv0 * mv0 + bv * (1.f - mv0);
        wq[r0 + j] = __builtin_convertvector(w0 * 65535.f + 0.5f, u16x4);
        f4 d0 = w0 - xv; s[0] += (double)hsum(d0 * d0);
        f4 tv1 = __builtin_nontemporal_load(&temps[r1 + j]);
        f4 mv1 = __builtin_nontemporal_load(&masks[r1 + j]);
        f4 w1 = tv1 * mv1 + bv * (1.f - mv1);
        wq[r1 + j] = __builtin_convertvector(w1 * 65535.f + 0.5f, u16x4);
        f4 d1 = w1 - xv; s[1] += (double)hsum(d1 * d1);
        f4 tv2 = __builtin_nontemporal_load(&temps[r2 + j]);
        f4 mv2 = __builtin_nontemporal_load(&masks[r2 + j]);
        f4 w2 = tv2 * mv2 + bv * (1.f - mv2);
        wq[r2 + j] = __builtin_convertvector(w2 * 65535.f + 0.5f, u16x4);
        f4 d2 = w2 - xv; s[2] += (double)hsum(d2 * d2);
        f4 tv3 = __builtin_nontemporal_load(&temps[r3 + j]);
        f4 mv3 = __builtin_nontemporal_load(&masks[r3 + j]);
        f4 w3 = tv3 * mv3 + bv * (1.f - mv3);
        wq[r3 + j] = __builtin_convertvector(w3 * 65535.f + 0.5f, u16x4);
        f4 d3 = w3 - xv; s[3] += (double)hsum(d3 * d3);
    }
    blk_reduce4(s);
    if (tid == 0)
        for (int k = 0; k < 4; ++k) err32[b * TP1 + tbase + k] = s[k];
}

// Screen pass, 4 t-rows per block: score = sum(d^2), d = fma(q, Ms, -r)
// (the 1/65535 dequant cancels against Ms = M/65535). t0 block: exact t=0 score
// + D = sum(M*(M+|r|)) for the sound margin.
__global__ void k_errs(const u16x8* __restrict__ wq,
                       const f8* __restrict__ Ms, const f8* __restrict__ R,
                       const int* __restrict__ used,
                       double* __restrict__ err16, double* __restrict__ Dd) {
    const int lin = blockIdx.x;
    const int wg = (lin & 7) * BCHUNK + (lin >> 3);
    const int b = wg / RB, rg = wg - b * RB;
    const int tid = threadIdx.x;
    const f8* msb = Ms + (size_t)b * HW8;
    const f8* rb  = R  + (size_t)b * HW8;
    if (rg == RB - 1) {
        double s = 0.0, d = 0.0;
        for (int j = tid; j < HW8; j += 256) {
            f8 ms = msb[j], rr = rb[j];
            f8 M = ms * 65535.f;
            f8 dd = M * 5.f - rr;
            s += (double)hsum8(dd * dd);
            d += (double)hsum8(M * (M + fabs8(rr)));
        }
        blk_reduce2(s, d);
        if (tid == 0) { err16[b * TP1 + 0] = s; Dd[b] = d; }
        return;
    }
    const int tbase = 1 + rg * 4;
    const size_t r0 = ((size_t)(b * TT + tbase - 1)) * HW8;
    const size_t r1 = r0 + HW8, r2 = r1 + HW8, r3 = r2 + HW8;
    double s[4] = {0.0, 0.0, 0.0, 0.0};
    #pragma unroll 2
    for (int j = tid; j < HW8; j += 256) {
        f8 ms = msb[j], rr = rb[j];
        f8 q0 = __builtin_convertvector(wq[r0 + j], f8);
        f8 d0 = q0 * ms - rr; s[0] += (double)hsum8(d0 * d0);
        f8 q1 = __builtin_convertvector(wq[r1 + j], f8);
        f8 d1 = q1 * ms - rr; s[1] += (double)hsum8(d1 * d1);
        f8 q2 = __builtin_convertvector(wq[r2 + j], f8);
        f8 d2 = q2 * ms - rr; s[2] += (double)hsum8(d2 * d2);
        f8 q3 = __builtin_convertvector(wq[r3 + j], f8);
        f8 d3 = q3 * ms - rr; s[3] += (double)hsum8(d3 * d3);
    }
    blk_reduce4(s);
    if (tid == 0)
        for (int k = 0; k < 4; ++k) {
            int t = tbase + k;
            err16[b * TP1 + t] = used[b * TP1 + t] ? BIGE : s[k];
        }
}

// Sound refine (R6/R8-proven, parallel per-candidate): shortlist = {t: s <= min+margin};
// singleton -> screen argmin IS the true argmin, no re-eval; else exact f32 eval.
__global__ void k_refine(const f4* __restrict__ temps, const f4* __restrict__ masks,
                         const f4* __restrict__ bg,
                         const f4* __restrict__ Ms4, const f4* __restrict__ R4,
                         const double* __restrict__ err16, const double* __restrict__ Dd,
                         double* __restrict__ err32) {
    const int lin = blockIdx.x;
    const int wg = (lin & 7) * RCHUNK + (lin >> 3);
    const int b = wg / TP1, t = wg - b * TP1;
    const int tid = threadIdx.x;
    double e = (tid < TP1) ? err16[b * TP1 + tid] : 1e300;
    double m = e;
    for (int off = 32; off; off >>= 1) {
        double o = __shfl_down(m, off);
        m = (o < m) ? o : m;
    }
    __shared__ double sm[4]; __shared__ double smin_s; __shared__ int scnt[4];
    if ((tid & 63) == 0) sm[tid >> 6] = m;
    __syncthreads();
    if (tid == 0) {
        double a = (sm[0] < sm[1]) ? sm[0] : sm[1];
        double c = (sm[2] < sm[3]) ? sm[2] : sm[3];
        smin_s = (a < c) ? a : c;
    }
    __syncthreads();
    const double thr = smin_s + (6.0 * EPSQ * Dd[b] + 0.15);
    int flag = (tid < TP1) && (e <= thr);
    unsigned long long bal = __ballot(flag);
    if ((tid & 63) == 0) scnt[tid >> 6] = __popcll(bal);
    __syncthreads();
    const int cnt = scnt[0] + scnt[1] + scnt[2] + scnt[3];
    const double mys = err16[b * TP1 + t];
    if (mys > thr) { if (tid == 0) err32[b * TP1 + t] = BIGE; return; }
    if (cnt == 1 || t == 0) { if (tid == 0) err32[b * TP1 + t] = mys; return; }
    const size_t row = ((size_t)(b * TT + t - 1)) * HW4;
    const f4* msb = Ms4 + (size_t)b * HW4;
    const f4* rb  = R4  + (size_t)b * HW4;
    double s = 0.0;
    for (int j = tid; j < HW4; j += 256) {
        f4 tv = temps[row + j], mv = masks[row + j], bv = bg[j];
        f4 w = tv * mv + bv * (1.f - mv);
        f4 M = msb[j] * 65535.f;
        f4 d = w * M - rb[j];
        s += (double)hsum(d * d);
    }
    double tot = blk_reduce(s);
    if (tid == 0) err32[b * TP1 + t] = tot;
}

// Fused argmin + state update (Ms,r streams) + object emit + bookkeeping.
// LAST step emits recons = A + M*bg (affine dead-leaves identity).
template <bool FIRST, bool LAST>
__global__ void k_upd(const f4* __restrict__ temps, const f4* __restrict__ masks,
                      const f4* __restrict__ x, const f4* __restrict__ bg,
                      const double* __restrict__ err,
                      int* __restrict__ used, f4* __restrict__ Ms4, f4* __restrict__ R4,
                      f4* __restrict__ out_obj, f4* __restrict__ out_msk,
                      f4* __restrict__ out_rec, float* __restrict__ out_ids, int l) {
    const int lin = blockIdx.x;
    const int wg = (lin & 7) * 32 + (lin >> 3);    // 256 = 8*32 bijective
    const int tid = threadIdx.x;
    const int gid = wg * 256 + tid;
    const int b = gid >> 12;
    const int p = gid & (HW4 - 1);
    __shared__ int ssel;
    if (tid < 64) {
        double best = 1e301; int bi = TP1;
        for (int t = tid; t < TP1; t += 64) {
            double e = err[b * TP1 + t];
            if (e < best) { best = e; bi = t; }   // ascending t per thread: < keeps first
        }
        for (int off = 32; off; off >>= 1) {
            double oe = __shfl_down(best, off);
            int    oi = __shfl_down(bi, off);
            if (oe < best || (oe == best && oi < bi)) { best = oe; bi = oi; }
        }
        if (tid == 0) ssel = bi;
    }
    __syncthreads();
    const int id = ssel;
    f4 st, sm_;
    if (id == 0) { st = (f4){5.f,5.f,5.f,5.f}; sm_ = (f4){1.f,1.f,1.f,1.f}; }
    else {
        size_t base = ((size_t)(b * TT + id - 1)) * HW4 + p;
        st = temps[base]; sm_ = masks[base];
    }
    f4 xv = x[gid];
    f4 a, mp;
    if (FIRST) { a = (f4){0.f,0.f,0.f,0.f}; mp = (f4){1.f,1.f,1.f,1.f}; }
    else       { mp = Ms4[gid] * 65535.f; a = xv - R4[gid]; }
    a = a + mp * st * sm_;
    mp = mp * (1.f - sm_);
    const size_t ob = ((size_t)(b * LL + l)) * HW4 + p;
    out_obj[ob] = st;
    out_msk[ob] = sm_;
    if (LAST) {
        out_rec[gid] = a + mp * bg[p];
    } else {
        Ms4[gid] = mp * (1.f / 65535.f);
        R4[gid]  = xv - a;
    }
    if ((wg & 15) == 0 && tid == 0) {   // one block per batch
        if (id != 0) used[b * TP1 + id] = 1;
        out_ids[b * LL + l] = (float)id;
    }
}

// ---------- fallback path (small ws): exact d-form per (b,t) ----------
__global__ void k_init0(const f4* __restrict__ x, f4* __restrict__ Ms4, f4* __restrict__ R4,
                        int* __restrict__ used) {
    int gid = blockIdx.x * blockDim.x + threadIdx.x;
    if (gid < BB * TP1) used[gid] = 0;
    if (gid >= BB * HW4) return;
    float msv = (float)(1.0 / 65535.0);
    Ms4[gid] = (f4){msv, msv, msv, msv};
    R4[gid] = x[gid];
}

__global__ void k_errfb(const f4* __restrict__ temps, const f4* __restrict__ masks,
                        const f4* __restrict__ bg,
                        const f4* __restrict__ Ms4, const f4* __restrict__ R4,
                        const int* __restrict__ used, double* __restrict__ err32) {
    const int lin = blockIdx.x;
    const int wg = (lin & 7) * RCHUNK + (lin >> 3);
    const int b = wg / TP1, t = wg - b * TP1;
    const int tid = threadIdx.x;
    if (t != 0 && used[b * TP1 + t]) {
        if (tid == 0) err32[b * TP1 + t] = BIGE;
        return;
    }
    const f4* msb = Ms4 + (size_t)b * HW4;
    const f4* rb  = R4  + (size_t)b * HW4;
    double s = 0.0;
    if (t == 0) {
        for (int j = tid; j < HW4; j += 256) {
            f4 M = msb[j] * 65535.f;
            f4 d = M * 5.f - rb[j];
            s += (double)hsum(d * d);
        }
    } else {
        const size_t row = ((size_t)(b * TT + t - 1)) * HW4;
        for (int j = tid; j < HW4; j += 256) {
            f4 tv = temps[row + j], mv = masks[row + j], bv = bg[j];
            f4 w = tv * mv + bv * (1.f - mv);
            f4 M = msb[j] * 65535.f;
            f4 d = w * M - rb[j];
            s += (double)hsum(d * d);
        }
    }
    double tot = blk_reduce(s);
    if (tid == 0) err32[b * TP1 + t] = tot;
}

extern "C" void kernel_launch(void* const* d_in, const int* in_sizes, int n_in,
                              void* d_out, int out_size, void* d_ws, size_t ws_size,
                              hipStream_t stream) {
    const f4* x     = (const f4*)d_in[0];
    const f4* temps = (const f4*)d_in[1];
    const f4* masks = (const f4*)d_in[2];
    const f4* bg    = (const f4*)d_in[3];

    float* out      = (float*)d_out;
    f4*    out_rec  = (f4*)out;                           // B*HW
    f4*    out_obj  = (f4*)(out + 262144);                // B*L*HW
    f4*    out_msk  = (f4*)(out + 262144 + 1572864);      // B*L*HW
    float* out_ids  = out + 262144 + 2 * 1572864;         // B*L

    char* ws = (char*)d_ws;
    f4*     Ms4   = (f4*)(ws + OFF_MS);
    f4*     R4    = (f4*)(ws + OFF_R);
    double* err32 = (double*)(ws + OFF_E32);
    double* err16 = (double*)(ws + OFF_E16);
    double* Dd    = (double*)(ws + OFF_D);
    int*    used  = (int*)(ws + OFF_USED);
    u16x4*  wq    = (u16x4*)(ws + OFF_WQ);

    const bool full = (ws_size >= WS_FULL);

    if (full) {
        k_build<<<NBLK, 256, 0, stream>>>(temps, masks, bg, x, wq, err32, used);
        k_upd<true, false><<<256, 256, 0, stream>>>(temps, masks, x, bg, err32, used,
                                                    Ms4, R4, out_obj, out_msk, out_rec, out_ids, 0);
        for (int l = 1; l < LL; ++l) {
            k_errs<<<NBLK, 256, 0, stream>>>((const u16x8*)wq, (const f8*)Ms4, (const f8*)R4,
                                             used, err16, Dd);
            k_refine<<<BB * TP1, 256, 0, stream>>>(temps, masks, bg, Ms4, R4, err16, Dd, err32);
            if (l < LL - 1)
                k_upd<false, false><<<256, 256, 0, stream>>>(temps, masks, x, bg, err32, used,
                                                             Ms4, R4, out_obj, out_msk, out_rec, out_ids, l);
            else
                k_upd<false, true><<<256, 256, 0, stream>>>(temps, masks, x, bg, err32, used,
                                                            Ms4, R4, out_obj, out_msk, out_rec, out_ids, l);
        }
    } else {
        k_init0<<<(BB * HW4 + 255) / 256, 256, 0, stream>>>(x, Ms4, R4, used);
        for (int l = 0; l < LL; ++l) {
            k_errfb<<<BB * TP1, 256, 0, stream>>>(temps, masks, bg, Ms4, R4, used, err32);
            if (l == 0)
                k_upd<true, false><<<256, 256, 0, stream>>>(temps, masks, x, bg, err32, used,
                                                            Ms4, R4, out_obj, out_msk, out_rec, out_ids, l);
            else if (l == LL - 1)
                k_upd<false, true><<<256, 256, 0, stream>>>(temps, masks, x, bg, err32, used,
                                                            Ms4, R4, out_obj, out_msk, out_rec, out_ids, l);
            else
                k_upd<false, false><<<256, 256, 0, stream>>>(temps, masks, x, bg, err32, used,
                                                             Ms4, R4, out_obj, out_msk, out_rec, out_ids, l);
        }
    }
}